// Round 1
// baseline (315.709 us; speedup 1.0000x reference)
//
#include <hip/hip_runtime.h>
#include <stdint.h>

typedef unsigned short u16;
typedef __bf16 bf8 __attribute__((ext_vector_type(8)));
typedef float f4 __attribute__((ext_vector_type(4)));

#define S_ 2048
#define D_ 1024
#define H_ 16
#define HD_ 64
#define M_ 4096

__device__ __forceinline__ u16 f2bf(float f) {
  union { float f; uint32_t u; } v; v.f = f;
  uint32_t u = v.u;
  u += 0x7FFF + ((u >> 16) & 1);   // round-to-nearest-even
  return (u16)(u >> 16);
}

__device__ __forceinline__ void load_lds16(const void* g, void* l) {
  __builtin_amdgcn_global_load_lds(
      (const __attribute__((address_space(1))) void*)g,
      (__attribute__((address_space(3))) void*)l, 16, 0, 0);
}

// ---------------- LayerNorm: x f32 -> h bf16 ----------------
__global__ __launch_bounds__(256) void ln_kernel(
    const float* __restrict__ x, const float* __restrict__ gamma,
    const float* __restrict__ beta, u16* __restrict__ hbf) {
  int row = blockIdx.x;
  int tid = threadIdx.x;
  int w = tid >> 6, lane = tid & 63;
  const float* xr = x + (size_t)row * D_;
  float lv[4];
  float s = 0.f;
  #pragma unroll
  for (int i = 0; i < 4; ++i) { lv[i] = xr[tid + i * 256]; s += lv[i]; }
  __shared__ float red[8];
  #pragma unroll
  for (int off = 32; off >= 1; off >>= 1) s += __shfl_xor(s, off);
  if (lane == 0) red[w] = s;
  __syncthreads();
  float mean = (red[0] + red[1] + red[2] + red[3]) * (1.f / D_);
  float vs = 0.f;
  #pragma unroll
  for (int i = 0; i < 4; ++i) { float d = lv[i] - mean; vs += d * d; }
  #pragma unroll
  for (int off = 32; off >= 1; off >>= 1) vs += __shfl_xor(vs, off);
  if (lane == 0) red[4 + w] = vs;
  __syncthreads();
  float var = (red[4] + red[5] + red[6] + red[7]) * (1.f / D_);
  float rstd = rsqrtf(var + 1e-5f);
  #pragma unroll
  for (int i = 0; i < 4; ++i) {
    int col = tid + i * 256;
    float y = (lv[i] - mean) * rstd * gamma[col] + beta[col];
    hbf[(size_t)row * D_ + col] = f2bf(y);
  }
}

// ---------------- weight convert f32 -> bf16 ----------------
__global__ __launch_bounds__(256) void convw_kernel(
    const float* __restrict__ wq, const float* __restrict__ wk,
    const float* __restrict__ wv, const float* __restrict__ wo,
    u16* __restrict__ wqkv, u16* __restrict__ wobf) {
  int idx = blockIdx.x * 256 + threadIdx.x;   // 0 .. 4M-1
  int part = idx >> 20;
  int off = idx & 0xFFFFF;
  const float* src = part == 0 ? wq : part == 1 ? wk : part == 2 ? wv : wo;
  float v = src[off];
  if (part < 3) wqkv[idx] = f2bf(v);
  else wobf[off] = f2bf(v);
}

// ---------------- QKV GEMM: C[4096,3072] = h @ Wqkv^T, scatter epilogue ----
__global__ __launch_bounds__(256) void gemm_qkv_kernel(
    const u16* __restrict__ A,    // [4096][1024] bf16
    const u16* __restrict__ W,    // [3072][1024] bf16
    const float* __restrict__ bq, const float* __restrict__ bk,
    const float* __restrict__ bv,
    u16* __restrict__ Qb, u16* __restrict__ Kb, float* __restrict__ Vf) {
  __shared__ u16 As[128 * 64];
  __shared__ u16 Bs[128 * 64];
  const int tid = threadIdx.x;
  const int w = tid >> 6, lane = tid & 63;
  const int wr = w >> 1, wc = w & 1;
  const int m0 = blockIdx.y * 128, n0 = blockIdx.x * 128;
  const int lr = lane & 15, lkb = (lane >> 4) * 8;
  f4 zero = {0.f, 0.f, 0.f, 0.f};
  f4 acc[4][4];
  #pragma unroll
  for (int i = 0; i < 4; ++i)
    #pragma unroll
    for (int j = 0; j < 4; ++j) acc[i][j] = zero;

  for (int kt = 0; kt < 16; ++kt) {
    #pragma unroll
    for (int c = 0; c < 4; ++c) {
      int e = c * 2048 + tid * 8;
      int row = e >> 6, col = e & 63;
      load_lds16(A + (size_t)(m0 + row) * 1024 + kt * 64 + col,
                 &As[c * 2048 + w * 512]);
      load_lds16(W + (size_t)(n0 + row) * 1024 + kt * 64 + col,
                 &Bs[c * 2048 + w * 512]);
    }
    __syncthreads();
    #pragma unroll
    for (int kk = 0; kk < 64; kk += 32) {
      bf8 af[4], bfr[4];
      #pragma unroll
      for (int i = 0; i < 4; ++i)
        af[i] = *(const bf8*)&As[(wr * 64 + i * 16 + lr) * 64 + kk + lkb];
      #pragma unroll
      for (int j = 0; j < 4; ++j)
        bfr[j] = *(const bf8*)&Bs[(wc * 64 + j * 16 + lr) * 64 + kk + lkb];
      #pragma unroll
      for (int i = 0; i < 4; ++i)
        #pragma unroll
        for (int j = 0; j < 4; ++j)
          acc[i][j] = __builtin_amdgcn_mfma_f32_16x16x32_bf16(
              af[i], bfr[j], acc[i][j], 0, 0, 0);
    }
    __syncthreads();
  }

  #pragma unroll
  for (int i = 0; i < 4; ++i) {
    #pragma unroll
    for (int j = 0; j < 4; ++j) {
      #pragma unroll
      for (int r = 0; r < 4; ++r) {
        int m = m0 + wr * 64 + i * 16 + (lane >> 4) * 4 + r;
        int n = n0 + wc * 64 + j * 16 + lr;
        int part = n >> 10, col = n & 1023;
        float bias = part == 0 ? bq[col] : (part == 1 ? bk[col] : bv[col]);
        float val = acc[i][j][r] + bias;
        int b = m >> 11, s = m & 2047;
        int hh = col >> 6, d = col & 63;
        size_t idx = ((size_t)(b * H_ + hh) * S_ + s) * HD_ + d;
        if (part == 0) Qb[idx] = f2bf(val);
        else if (part == 1) Kb[idx] = f2bf(val);
        else Vf[idx] = val;
      }
    }
  }
}

// ---------------- scores upper-triangle: Z(q) = q + sum_{k>=q} exp(s_qk) ----
__global__ __launch_bounds__(256) void scores_z_kernel(
    const u16* __restrict__ Qb, const u16* __restrict__ Kb,
    float* __restrict__ Z, float* __restrict__ Ed) {
  int bh = blockIdx.y;
  int qb = blockIdx.x;
  int w = threadIdx.x >> 6, lane = threadIdx.x & 63;
  int lr = lane & 15, lkb = (lane >> 4) * 8;
  const u16* Qh = Qb + (size_t)bh * S_ * HD_;
  const u16* Kh = Kb + (size_t)bh * S_ * HD_;
  int q0 = qb * 64 + w * 16;
  bf8 a0 = *(const bf8*)&Qh[(q0 + lr) * 64 + lkb];
  bf8 a1 = *(const bf8*)&Qh[(q0 + lr) * 64 + 32 + lkb];
  float zacc[4] = {0.f, 0.f, 0.f, 0.f};
  int kt0 = q0 >> 4;
  for (int kt = kt0; kt < S_ / 16; ++kt) {
    bf8 b0 = *(const bf8*)&Kh[(kt * 16 + lr) * 64 + lkb];
    bf8 b1 = *(const bf8*)&Kh[(kt * 16 + lr) * 64 + 32 + lkb];
    f4 c = {0.f, 0.f, 0.f, 0.f};
    c = __builtin_amdgcn_mfma_f32_16x16x32_bf16(a0, b0, c, 0, 0, 0);
    c = __builtin_amdgcn_mfma_f32_16x16x32_bf16(a1, b1, c, 0, 0, 0);
    int kcol = kt * 16 + lr;
    #pragma unroll
    for (int r = 0; r < 4; ++r) {
      int qrow = q0 + (lane >> 4) * 4 + r;
      float s = c[r] * 0.03125f;     // / sqrt(1024)
      float e = __expf(s);
      if (kcol > qrow) {
        zacc[r] += e;
      } else if (kcol == qrow) {
        zacc[r] += e;
        Ed[(size_t)bh * S_ + qrow] = e;
      }
    }
  }
  #pragma unroll
  for (int r = 0; r < 4; ++r) {
    float v = zacc[r];
    v += __shfl_xor(v, 1);
    v += __shfl_xor(v, 2);
    v += __shfl_xor(v, 4);
    v += __shfl_xor(v, 8);
    if (lr == 0) {
      int qrow = q0 + (lane >> 4) * 4 + r;
      Z[(size_t)bh * S_ + qrow] = (float)qrow + v;
    }
  }
}

// ---------------- V prefix-sum chain ----------------
__global__ __launch_bounds__(64) void vchunk_kernel(
    const float* __restrict__ Vf, float* __restrict__ csum) {
  int bh = blockIdx.y, c = blockIdx.x;
  int d = threadIdx.x;
  const float* vp = Vf + ((size_t)bh * S_ + c * 64) * HD_ + d;
  float s = 0.f;
  for (int r = 0; r < 64; ++r) s += vp[r * HD_];
  csum[((size_t)bh * 32 + c) * HD_ + d] = s;
}

__global__ __launch_bounds__(64) void vprefix_kernel(float* __restrict__ csum) {
  int bh = blockIdx.x;
  int d = threadIdx.x;
  float run = 0.f;
  for (int c = 0; c < 32; ++c) {
    size_t i = ((size_t)bh * 32 + c) * HD_ + d;
    float v = csum[i];
    csum[i] = run;   // exclusive prefix
    run += v;
  }
}

__global__ __launch_bounds__(64) void attn_out_kernel(
    const float* __restrict__ Vf, const float* __restrict__ csum,
    const float* __restrict__ Z, const float* __restrict__ Ed,
    u16* __restrict__ concat) {
  int bh = blockIdx.y, c = blockIdx.x;
  int d = threadIdx.x;
  int b = bh >> 4, h = bh & 15;
  float run = csum[((size_t)bh * 32 + c) * HD_ + d];
  for (int r = 0; r < 64; ++r) {
    int s = c * 64 + r;
    size_t vi = ((size_t)bh * S_ + s) * HD_ + d;
    float v = Vf[vi];
    float z = Z[(size_t)bh * S_ + s];
    float e = Ed[(size_t)bh * S_ + s];
    float a = (run + e * v) / z;
    concat[(size_t)(b * S_ + s) * D_ + h * HD_ + d] = f2bf(a);
    run += v;
  }
}

// ---------------- output GEMM: out = x + concat @ wo^T + bo ----------------
__global__ __launch_bounds__(256) void gemm_out_kernel(
    const u16* __restrict__ A,    // concat bf16 [4096][1024]
    const u16* __restrict__ W,    // wo bf16 [1024][1024]
    const float* __restrict__ x, const float* __restrict__ bo,
    float* __restrict__ out) {
  __shared__ u16 As[128 * 64];
  __shared__ u16 Bs[128 * 64];
  const int tid = threadIdx.x;
  const int w = tid >> 6, lane = tid & 63;
  const int wr = w >> 1, wc = w & 1;
  const int m0 = blockIdx.y * 128, n0 = blockIdx.x * 128;
  const int lr = lane & 15, lkb = (lane >> 4) * 8;
  f4 zero = {0.f, 0.f, 0.f, 0.f};
  f4 acc[4][4];
  #pragma unroll
  for (int i = 0; i < 4; ++i)
    #pragma unroll
    for (int j = 0; j < 4; ++j) acc[i][j] = zero;

  for (int kt = 0; kt < 16; ++kt) {
    #pragma unroll
    for (int c = 0; c < 4; ++c) {
      int e = c * 2048 + tid * 8;
      int row = e >> 6, col = e & 63;
      load_lds16(A + (size_t)(m0 + row) * 1024 + kt * 64 + col,
                 &As[c * 2048 + w * 512]);
      load_lds16(W + (size_t)(n0 + row) * 1024 + kt * 64 + col,
                 &Bs[c * 2048 + w * 512]);
    }
    __syncthreads();
    #pragma unroll
    for (int kk = 0; kk < 64; kk += 32) {
      bf8 af[4], bfr[4];
      #pragma unroll
      for (int i = 0; i < 4; ++i)
        af[i] = *(const bf8*)&As[(wr * 64 + i * 16 + lr) * 64 + kk + lkb];
      #pragma unroll
      for (int j = 0; j < 4; ++j)
        bfr[j] = *(const bf8*)&Bs[(wc * 64 + j * 16 + lr) * 64 + kk + lkb];
      #pragma unroll
      for (int i = 0; i < 4; ++i)
        #pragma unroll
        for (int j = 0; j < 4; ++j)
          acc[i][j] = __builtin_amdgcn_mfma_f32_16x16x32_bf16(
              af[i], bfr[j], acc[i][j], 0, 0, 0);
    }
    __syncthreads();
  }

  #pragma unroll
  for (int i = 0; i < 4; ++i) {
    #pragma unroll
    for (int j = 0; j < 4; ++j) {
      #pragma unroll
      for (int r = 0; r < 4; ++r) {
        int m = m0 + wr * 64 + i * 16 + (lane >> 4) * 4 + r;
        int n = n0 + wc * 64 + j * 16 + lr;
        size_t oi = (size_t)m * D_ + n;
        out[oi] = x[oi] + acc[i][j][r] + bo[n];
      }
    }
  }
}

extern "C" void kernel_launch(void* const* d_in, const int* in_sizes, int n_in,
                              void* d_out, int out_size, void* d_ws, size_t ws_size,
                              hipStream_t stream) {
  (void)in_sizes; (void)n_in; (void)out_size; (void)ws_size;
  const float* x     = (const float*)d_in[0];
  const float* wq    = (const float*)d_in[1];
  const float* bq    = (const float*)d_in[2];
  const float* wk    = (const float*)d_in[3];
  const float* bk    = (const float*)d_in[4];
  const float* wv    = (const float*)d_in[5];
  const float* bv    = (const float*)d_in[6];
  const float* wo    = (const float*)d_in[7];
  const float* bo    = (const float*)d_in[8];
  const float* gamma = (const float*)d_in[9];
  const float* beta  = (const float*)d_in[10];
  float* out = (float*)d_out;

  char* ws = (char*)d_ws;
  u16* hbf    = (u16*)(ws);                               // 8 MB
  u16* wqkv   = (u16*)(ws + (8u << 20));                  // 6 MB
  u16* wobf   = (u16*)(ws + (14u << 20));                 // 2 MB
  u16* Qb     = (u16*)(ws + (16u << 20));                 // 8 MB
  u16* Kb     = (u16*)(ws + (24u << 20));                 // 8 MB
  float* Vf   = (float*)(ws + (32u << 20));               // 16 MB
  float* Z    = (float*)(ws + (48u << 20));               // 256 KB
  float* Ed   = (float*)(ws + (48u << 20) + (256u << 10));// 256 KB
  float* csum = (float*)(ws + (48u << 20) + (512u << 10));// 256 KB
  u16* concat = (u16*)(ws + (49u << 20));                 // 8 MB

  ln_kernel<<<dim3(4096), dim3(256), 0, stream>>>(x, gamma, beta, hbf);
  convw_kernel<<<dim3(16384), dim3(256), 0, stream>>>(wq, wk, wv, wo, wqkv, wobf);
  gemm_qkv_kernel<<<dim3(24, 32), dim3(256), 0, stream>>>(hbf, wqkv, bq, bk, bv,
                                                          Qb, Kb, Vf);
  scores_z_kernel<<<dim3(32, 32), dim3(256), 0, stream>>>(Qb, Kb, Z, Ed);
  vchunk_kernel<<<dim3(32, 32), dim3(64), 0, stream>>>(Vf, csum);
  vprefix_kernel<<<dim3(32), dim3(64), 0, stream>>>(csum);
  attn_out_kernel<<<dim3(32, 32), dim3(64), 0, stream>>>(Vf, csum, Z, Ed, concat);
  gemm_out_kernel<<<dim3(8, 32), dim3(256), 0, stream>>>(concat, wobf, x, bo, out);
}

// Round 2
// 264.764 us; speedup vs baseline: 1.1924x; 1.1924x over previous
//
#include <hip/hip_runtime.h>
#include <stdint.h>

typedef unsigned short u16;
typedef __bf16 bf8 __attribute__((ext_vector_type(8)));
typedef float f4 __attribute__((ext_vector_type(4)));

#define S_ 2048
#define D_ 1024
#define H_ 16
#define HD_ 64
#define M_ 4096

__device__ __forceinline__ u16 f2bf(float f) {
  union { float f; uint32_t u; } v; v.f = f;
  uint32_t u = v.u;
  u += 0x7FFF + ((u >> 16) & 1);   // round-to-nearest-even
  return (u16)(u >> 16);
}

__device__ __forceinline__ void load_lds16(const void* g, void* l) {
  __builtin_amdgcn_global_load_lds(
      (const __attribute__((address_space(1))) void*)g,
      (__attribute__((address_space(3))) void*)l, 16, 0, 0);
}

// ---------------- LayerNorm: x f32 -> h bf16 ----------------
__global__ __launch_bounds__(256) void ln_kernel(
    const float* __restrict__ x, const float* __restrict__ gamma,
    const float* __restrict__ beta, u16* __restrict__ hbf) {
  int row = blockIdx.x;
  int tid = threadIdx.x;
  int w = tid >> 6, lane = tid & 63;
  const float* xr = x + (size_t)row * D_;
  float lv[4];
  float s = 0.f;
  #pragma unroll
  for (int i = 0; i < 4; ++i) { lv[i] = xr[tid + i * 256]; s += lv[i]; }
  __shared__ float red[8];
  #pragma unroll
  for (int off = 32; off >= 1; off >>= 1) s += __shfl_xor(s, off);
  if (lane == 0) red[w] = s;
  __syncthreads();
  float mean = (red[0] + red[1] + red[2] + red[3]) * (1.f / D_);
  float vs = 0.f;
  #pragma unroll
  for (int i = 0; i < 4; ++i) { float d = lv[i] - mean; vs += d * d; }
  #pragma unroll
  for (int off = 32; off >= 1; off >>= 1) vs += __shfl_xor(vs, off);
  if (lane == 0) red[4 + w] = vs;
  __syncthreads();
  float var = (red[4] + red[5] + red[6] + red[7]) * (1.f / D_);
  float rstd = rsqrtf(var + 1e-5f);
  #pragma unroll
  for (int i = 0; i < 4; ++i) {
    int col = tid + i * 256;
    float y = (lv[i] - mean) * rstd * gamma[col] + beta[col];
    hbf[(size_t)row * D_ + col] = f2bf(y);
  }
}

// ---------------- weight convert f32 -> bf16 ----------------
__global__ __launch_bounds__(256) void convw_kernel(
    const float* __restrict__ wq, const float* __restrict__ wk,
    const float* __restrict__ wv, const float* __restrict__ wo,
    u16* __restrict__ wqkv, u16* __restrict__ wobf) {
  int idx = blockIdx.x * 256 + threadIdx.x;   // 0 .. 4M-1
  int part = idx >> 20;
  int off = idx & 0xFFFFF;
  const float* src = part == 0 ? wq : part == 1 ? wk : part == 2 ? wv : wo;
  float v = src[off];
  if (part < 3) wqkv[idx] = f2bf(v);
  else wobf[off] = f2bf(v);
}

// ---------------- QKV GEMM: C[4096,3072] = h @ Wqkv^T, scatter epilogue ----
__global__ __launch_bounds__(256) void gemm_qkv_kernel(
    const u16* __restrict__ A,    // [4096][1024] bf16
    const u16* __restrict__ W,    // [3072][1024] bf16
    const float* __restrict__ bq, const float* __restrict__ bk,
    const float* __restrict__ bv,
    u16* __restrict__ Qb, u16* __restrict__ Kb, float* __restrict__ Vf) {
  __shared__ u16 As[128 * 64];
  __shared__ u16 Bs[128 * 64];
  const int tid = threadIdx.x;
  const int w = tid >> 6, lane = tid & 63;
  const int wr = w >> 1, wc = w & 1;
  const int m0 = blockIdx.y * 128, n0 = blockIdx.x * 128;
  const int lr = lane & 15, lkb = (lane >> 4) * 8;
  f4 zero = {0.f, 0.f, 0.f, 0.f};
  f4 acc[4][4];
  #pragma unroll
  for (int i = 0; i < 4; ++i)
    #pragma unroll
    for (int j = 0; j < 4; ++j) acc[i][j] = zero;

  for (int kt = 0; kt < 16; ++kt) {
    #pragma unroll
    for (int c = 0; c < 4; ++c) {
      int e = c * 2048 + tid * 8;
      int row = e >> 6, col = e & 63;
      load_lds16(A + (size_t)(m0 + row) * 1024 + kt * 64 + col,
                 &As[c * 2048 + w * 512]);
      load_lds16(W + (size_t)(n0 + row) * 1024 + kt * 64 + col,
                 &Bs[c * 2048 + w * 512]);
    }
    __syncthreads();
    #pragma unroll
    for (int kk = 0; kk < 64; kk += 32) {
      bf8 af[4], bfr[4];
      #pragma unroll
      for (int i = 0; i < 4; ++i)
        af[i] = *(const bf8*)&As[(wr * 64 + i * 16 + lr) * 64 + kk + lkb];
      #pragma unroll
      for (int j = 0; j < 4; ++j)
        bfr[j] = *(const bf8*)&Bs[(wc * 64 + j * 16 + lr) * 64 + kk + lkb];
      #pragma unroll
      for (int i = 0; i < 4; ++i)
        #pragma unroll
        for (int j = 0; j < 4; ++j)
          acc[i][j] = __builtin_amdgcn_mfma_f32_16x16x32_bf16(
              af[i], bfr[j], acc[i][j], 0, 0, 0);
    }
    __syncthreads();
  }

  #pragma unroll
  for (int i = 0; i < 4; ++i) {
    #pragma unroll
    for (int j = 0; j < 4; ++j) {
      #pragma unroll
      for (int r = 0; r < 4; ++r) {
        int m = m0 + wr * 64 + i * 16 + (lane >> 4) * 4 + r;
        int n = n0 + wc * 64 + j * 16 + lr;
        int part = n >> 10, col = n & 1023;
        float bias = part == 0 ? bq[col] : (part == 1 ? bk[col] : bv[col]);
        float val = acc[i][j][r] + bias;
        int b = m >> 11, s = m & 2047;
        int hh = col >> 6, d = col & 63;
        size_t idx = ((size_t)(b * H_ + hh) * S_ + s) * HD_ + d;
        if (part == 0) Qb[idx] = f2bf(val);
        else if (part == 1) Kb[idx] = f2bf(val);
        else Vf[idx] = val;
      }
    }
  }
}

// ---------------- scores upper-triangle: Z(q) = q + sum_{k>=q} exp(s_qk) ----
// Block = (qb: 64 q-rows, bh). 4 waves split the K-tile range (stride 4).
// Q fragments for all 4 row-groups held in registers; K streamed from L2.
__global__ __launch_bounds__(256) void scores_z_kernel(
    const u16* __restrict__ Qb, const u16* __restrict__ Kb,
    float* __restrict__ Z, float* __restrict__ Ed) {
  int bh = blockIdx.y;
  int qb = blockIdx.x;
  int tid = threadIdx.x;
  int w = tid >> 6, lane = tid & 63;
  int lr = lane & 15, hi = lane >> 4, lkb = hi * 8;
  const u16* Qh = Qb + (size_t)bh * S_ * HD_;
  const u16* Kh = Kb + (size_t)bh * S_ * HD_;
  int q0 = qb * 64;
  bf8 a[4][2];
  #pragma unroll
  for (int g = 0; g < 4; ++g) {
    a[g][0] = *(const bf8*)&Qh[(q0 + g * 16 + lr) * 64 + lkb];
    a[g][1] = *(const bf8*)&Qh[(q0 + g * 16 + lr) * 64 + 32 + lkb];
  }
  float zacc[4][4];
  #pragma unroll
  for (int g = 0; g < 4; ++g)
    #pragma unroll
    for (int r = 0; r < 4; ++r) zacc[g][r] = 0.f;

  const int NT = S_ / 16;   // 128
  int kt0 = qb * 4;
  for (int kt = kt0 + w; kt < NT; kt += 4) {
    bf8 b0 = *(const bf8*)&Kh[(kt * 16 + lr) * 64 + lkb];
    bf8 b1 = *(const bf8*)&Kh[(kt * 16 + lr) * 64 + 32 + lkb];
    int kcol = kt * 16 + lr;
    #pragma unroll
    for (int g = 0; g < 4; ++g) {
      f4 c = {0.f, 0.f, 0.f, 0.f};
      c = __builtin_amdgcn_mfma_f32_16x16x32_bf16(a[g][0], b0, c, 0, 0, 0);
      c = __builtin_amdgcn_mfma_f32_16x16x32_bf16(a[g][1], b1, c, 0, 0, 0);
      #pragma unroll
      for (int r = 0; r < 4; ++r) {
        int qrow = q0 + g * 16 + hi * 4 + r;
        float e = __expf(c[r] * 0.03125f);    // / sqrt(1024)
        if (kcol > qrow) {
          zacc[g][r] += e;
        } else if (kcol == qrow) {
          zacc[g][r] += e;
          Ed[(size_t)bh * S_ + qrow] = e;
        }
      }
    }
  }
  __shared__ float Zp[4][64];
  #pragma unroll
  for (int g = 0; g < 4; ++g) {
    #pragma unroll
    for (int r = 0; r < 4; ++r) {
      float v = zacc[g][r];
      v += __shfl_xor(v, 1);
      v += __shfl_xor(v, 2);
      v += __shfl_xor(v, 4);
      v += __shfl_xor(v, 8);
      if (lr == 0) Zp[w][g * 16 + hi * 4 + r] = v;
    }
  }
  __syncthreads();
  if (tid < 64) {
    float z = (float)(q0 + tid) + Zp[0][tid] + Zp[1][tid] + Zp[2][tid] + Zp[3][tid];
    Z[(size_t)bh * S_ + q0 + tid] = z;
  }
}

// ---------------- V prefix-sum chain (16-row chunks) ----------------
#define NC_ 128   // chunks per bh (16 rows each)

__global__ __launch_bounds__(64) void vchunk_kernel(
    const float* __restrict__ Vf, float* __restrict__ csum) {
  int bh = blockIdx.y, c = blockIdx.x;
  int d = threadIdx.x;
  const float* vp = Vf + ((size_t)bh * S_ + c * 16) * HD_ + d;
  float s = 0.f;
  #pragma unroll
  for (int r = 0; r < 16; ++r) s += vp[r * HD_];
  csum[((size_t)bh * NC_ + c) * HD_ + d] = s;
}

// per-bh exclusive scan over 128 chunk sums; 256 thr: d = tid&63, quarter = tid>>6
__global__ __launch_bounds__(256) void vprefix_kernel(float* __restrict__ csum) {
  int bh = blockIdx.x;
  int d = threadIdx.x & 63;
  int qt = threadIdx.x >> 6;
  __shared__ float tot[4][64];
  float run = 0.f;
  #pragma unroll
  for (int c = 0; c < 32; ++c) {
    size_t i = ((size_t)bh * NC_ + qt * 32 + c) * HD_ + d;
    float v = csum[i];
    csum[i] = run;
    run += v;
  }
  tot[qt][d] = run;
  __syncthreads();
  float off = 0.f;
  for (int p = 0; p < 4; ++p) if (p < qt) off += tot[p][d];
  if (off != 0.f) {
    #pragma unroll
    for (int c = 0; c < 32; ++c) {
      size_t i = ((size_t)bh * NC_ + qt * 32 + c) * HD_ + d;
      csum[i] += off;
    }
  }
}

__global__ __launch_bounds__(64) void attn_out_kernel(
    const float* __restrict__ Vf, const float* __restrict__ csum,
    const float* __restrict__ Z, const float* __restrict__ Ed,
    u16* __restrict__ concat) {
  int bh = blockIdx.y, c = blockIdx.x;
  int d = threadIdx.x;
  int b = bh >> 4, h = bh & 15;
  float run = csum[((size_t)bh * NC_ + c) * HD_ + d];
  #pragma unroll
  for (int r = 0; r < 16; ++r) {
    int s = c * 16 + r;
    size_t vi = ((size_t)bh * S_ + s) * HD_ + d;
    float v = Vf[vi];
    float z = Z[(size_t)bh * S_ + s];
    float e = Ed[(size_t)bh * S_ + s];
    float a = (run + e * v) / z;
    concat[(size_t)(b * S_ + s) * D_ + h * HD_ + d] = f2bf(a);
    run += v;
  }
}

// ---------------- output GEMM: out = x + concat @ wo^T + bo ----------------
__global__ __launch_bounds__(256) void gemm_out_kernel(
    const u16* __restrict__ A,    // concat bf16 [4096][1024]
    const u16* __restrict__ W,    // wo bf16 [1024][1024]
    const float* __restrict__ x, const float* __restrict__ bo,
    float* __restrict__ out) {
  __shared__ u16 As[128 * 64];
  __shared__ u16 Bs[128 * 64];
  const int tid = threadIdx.x;
  const int w = tid >> 6, lane = tid & 63;
  const int wr = w >> 1, wc = w & 1;
  const int m0 = blockIdx.y * 128, n0 = blockIdx.x * 128;
  const int lr = lane & 15, lkb = (lane >> 4) * 8;
  f4 zero = {0.f, 0.f, 0.f, 0.f};
  f4 acc[4][4];
  #pragma unroll
  for (int i = 0; i < 4; ++i)
    #pragma unroll
    for (int j = 0; j < 4; ++j) acc[i][j] = zero;

  for (int kt = 0; kt < 16; ++kt) {
    #pragma unroll
    for (int c = 0; c < 4; ++c) {
      int e = c * 2048 + tid * 8;
      int row = e >> 6, col = e & 63;
      load_lds16(A + (size_t)(m0 + row) * 1024 + kt * 64 + col,
                 &As[c * 2048 + w * 512]);
      load_lds16(W + (size_t)(n0 + row) * 1024 + kt * 64 + col,
                 &Bs[c * 2048 + w * 512]);
    }
    __syncthreads();
    #pragma unroll
    for (int kk = 0; kk < 64; kk += 32) {
      bf8 af[4], bfr[4];
      #pragma unroll
      for (int i = 0; i < 4; ++i)
        af[i] = *(const bf8*)&As[(wr * 64 + i * 16 + lr) * 64 + kk + lkb];
      #pragma unroll
      for (int j = 0; j < 4; ++j)
        bfr[j] = *(const bf8*)&Bs[(wc * 64 + j * 16 + lr) * 64 + kk + lkb];
      #pragma unroll
      for (int i = 0; i < 4; ++i)
        #pragma unroll
        for (int j = 0; j < 4; ++j)
          acc[i][j] = __builtin_amdgcn_mfma_f32_16x16x32_bf16(
              af[i], bfr[j], acc[i][j], 0, 0, 0);
    }
    __syncthreads();
  }

  #pragma unroll
  for (int i = 0; i < 4; ++i) {
    #pragma unroll
    for (int j = 0; j < 4; ++j) {
      #pragma unroll
      for (int r = 0; r < 4; ++r) {
        int m = m0 + wr * 64 + i * 16 + (lane >> 4) * 4 + r;
        int n = n0 + wc * 64 + j * 16 + lr;
        size_t oi = (size_t)m * D_ + n;
        out[oi] = x[oi] + acc[i][j][r] + bo[n];
      }
    }
  }
}

extern "C" void kernel_launch(void* const* d_in, const int* in_sizes, int n_in,
                              void* d_out, int out_size, void* d_ws, size_t ws_size,
                              hipStream_t stream) {
  (void)in_sizes; (void)n_in; (void)out_size; (void)ws_size;
  const float* x     = (const float*)d_in[0];
  const float* wq    = (const float*)d_in[1];
  const float* bq    = (const float*)d_in[2];
  const float* wk    = (const float*)d_in[3];
  const float* bk    = (const float*)d_in[4];
  const float* wv    = (const float*)d_in[5];
  const float* bv    = (const float*)d_in[6];
  const float* wo    = (const float*)d_in[7];
  const float* bo    = (const float*)d_in[8];
  const float* gamma = (const float*)d_in[9];
  const float* beta  = (const float*)d_in[10];
  float* out = (float*)d_out;

  char* ws = (char*)d_ws;
  // layout (aliased where lifetimes allow):
  //  0- 8 MB : hbf (h bf16)              -- dead after gemm_qkv; csum aliases here
  //  8-14 MB : wqkv bf16
  // 14-16 MB : wobf bf16
  // 16-24 MB : Qb bf16                   -- dead after scores_z; concat aliases here
  // 24-32 MB : Kb bf16
  // 32-48 MB : Vf f32
  // 48    MB : Z (256 KB), Ed (256 KB)
  u16* hbf    = (u16*)(ws);
  u16* wqkv   = (u16*)(ws + (8u << 20));
  u16* wobf   = (u16*)(ws + (14u << 20));
  u16* Qb     = (u16*)(ws + (16u << 20));
  u16* Kb     = (u16*)(ws + (24u << 20));
  float* Vf   = (float*)(ws + (32u << 20));
  float* Z    = (float*)(ws + (48u << 20));
  float* Ed   = (float*)(ws + (48u << 20) + (256u << 10));
  float* csum = (float*)(ws);                 // aliases hbf (1 MB)
  u16* concat = (u16*)(ws + (16u << 20));     // aliases Qb (8 MB)

  ln_kernel<<<dim3(4096), dim3(256), 0, stream>>>(x, gamma, beta, hbf);
  convw_kernel<<<dim3(16384), dim3(256), 0, stream>>>(wq, wk, wv, wo, wqkv, wobf);
  gemm_qkv_kernel<<<dim3(24, 32), dim3(256), 0, stream>>>(hbf, wqkv, bq, bk, bv,
                                                          Qb, Kb, Vf);
  scores_z_kernel<<<dim3(32, 32), dim3(256), 0, stream>>>(Qb, Kb, Z, Ed);
  vchunk_kernel<<<dim3(NC_, 32), dim3(64), 0, stream>>>(Vf, csum);
  vprefix_kernel<<<dim3(32), dim3(256), 0, stream>>>(csum);
  attn_out_kernel<<<dim3(NC_, 32), dim3(64), 0, stream>>>(Vf, csum, Z, Ed, concat);
  gemm_out_kernel<<<dim3(8, 32), dim3(256), 0, stream>>>(concat, wobf, x, bo, out);
}

// Round 4
// 236.809 us; speedup vs baseline: 1.3332x; 1.1181x over previous
//
#include <hip/hip_runtime.h>
#include <stdint.h>

typedef unsigned short u16;
typedef __bf16 bf8 __attribute__((ext_vector_type(8)));
typedef float f4 __attribute__((ext_vector_type(4)));

#define S_ 2048
#define D_ 1024
#define H_ 16
#define HD_ 64
#define M_ 4096

__device__ __forceinline__ u16 f2bf(float f) {
  union { float f; uint32_t u; } v; v.f = f;
  uint32_t u = v.u;
  u += 0x7FFF + ((u >> 16) & 1);   // round-to-nearest-even
  return (u16)(u >> 16);
}

__device__ __forceinline__ void load_lds16(const void* g, void* l) {
  __builtin_amdgcn_global_load_lds(
      (const __attribute__((address_space(1))) void*)g,
      (__attribute__((address_space(3))) void*)l, 16, 0, 0);
}

// ---------------- LayerNorm: x f32 -> h bf16 ----------------
__global__ __launch_bounds__(256) void ln_kernel(
    const float* __restrict__ x, const float* __restrict__ gamma,
    const float* __restrict__ beta, u16* __restrict__ hbf) {
  int row = blockIdx.x;
  int tid = threadIdx.x;
  int w = tid >> 6, lane = tid & 63;
  const float* xr = x + (size_t)row * D_;
  float lv[4];
  float s = 0.f;
  #pragma unroll
  for (int i = 0; i < 4; ++i) { lv[i] = xr[tid + i * 256]; s += lv[i]; }
  __shared__ float red[8];
  #pragma unroll
  for (int off = 32; off >= 1; off >>= 1) s += __shfl_xor(s, off);
  if (lane == 0) red[w] = s;
  __syncthreads();
  float mean = (red[0] + red[1] + red[2] + red[3]) * (1.f / D_);
  float vs = 0.f;
  #pragma unroll
  for (int i = 0; i < 4; ++i) { float d = lv[i] - mean; vs += d * d; }
  #pragma unroll
  for (int off = 32; off >= 1; off >>= 1) vs += __shfl_xor(vs, off);
  if (lane == 0) red[4 + w] = vs;
  __syncthreads();
  float var = (red[4] + red[5] + red[6] + red[7]) * (1.f / D_);
  float rstd = rsqrtf(var + 1e-5f);
  #pragma unroll
  for (int i = 0; i < 4; ++i) {
    int col = tid + i * 256;
    float y = (lv[i] - mean) * rstd * gamma[col] + beta[col];
    hbf[(size_t)row * D_ + col] = f2bf(y);
  }
}

// ------ weight convert f32 -> bf16  (+ Z init: Z[bh][q] = q) ------
__global__ __launch_bounds__(256) void convw_kernel(
    const float* __restrict__ wq, const float* __restrict__ wk,
    const float* __restrict__ wv, const float* __restrict__ wo,
    u16* __restrict__ wqkv, u16* __restrict__ wobf, float* __restrict__ Z) {
  int idx = blockIdx.x * 256 + threadIdx.x;   // 0 .. 4M-1
  int part = idx >> 20;
  int off = idx & 0xFFFFF;
  const float* src = part == 0 ? wq : part == 1 ? wk : part == 2 ? wv : wo;
  float v = src[off];
  if (part < 3) wqkv[idx] = f2bf(v);
  else wobf[off] = f2bf(v);
  if (idx < 32 * S_) Z[idx] = (float)(idx & (S_ - 1));
}

// ---------------- QKV GEMM: C[4096,3072] = h @ Wqkv^T, scatter epilogue ----
__global__ __launch_bounds__(256) void gemm_qkv_kernel(
    const u16* __restrict__ A,    // [4096][1024] bf16
    const u16* __restrict__ W,    // [3072][1024] bf16
    const float* __restrict__ bq, const float* __restrict__ bk,
    const float* __restrict__ bv,
    u16* __restrict__ Qb, u16* __restrict__ Kb, float* __restrict__ Vf) {
  __shared__ u16 As[128 * 64];
  __shared__ u16 Bs[128 * 64];
  const int tid = threadIdx.x;
  const int w = tid >> 6, lane = tid & 63;
  const int wr = w >> 1, wc = w & 1;
  const int m0 = blockIdx.y * 128, n0 = blockIdx.x * 128;
  const int lr = lane & 15, lkb = (lane >> 4) * 8;
  f4 zero = {0.f, 0.f, 0.f, 0.f};
  f4 acc[4][4];
  #pragma unroll
  for (int i = 0; i < 4; ++i)
    #pragma unroll
    for (int j = 0; j < 4; ++j) acc[i][j] = zero;

  for (int kt = 0; kt < 16; ++kt) {
    #pragma unroll
    for (int c = 0; c < 4; ++c) {
      int e = c * 2048 + tid * 8;
      int row = e >> 6, col = e & 63;
      load_lds16(A + (size_t)(m0 + row) * 1024 + kt * 64 + col,
                 &As[c * 2048 + w * 512]);
      load_lds16(W + (size_t)(n0 + row) * 1024 + kt * 64 + col,
                 &Bs[c * 2048 + w * 512]);
    }
    __syncthreads();
    #pragma unroll
    for (int kk = 0; kk < 64; kk += 32) {
      bf8 af[4], bfr[4];
      #pragma unroll
      for (int i = 0; i < 4; ++i)
        af[i] = *(const bf8*)&As[(wr * 64 + i * 16 + lr) * 64 + kk + lkb];
      #pragma unroll
      for (int j = 0; j < 4; ++j)
        bfr[j] = *(const bf8*)&Bs[(wc * 64 + j * 16 + lr) * 64 + kk + lkb];
      #pragma unroll
      for (int i = 0; i < 4; ++i)
        #pragma unroll
        for (int j = 0; j < 4; ++j)
          acc[i][j] = __builtin_amdgcn_mfma_f32_16x16x32_bf16(
              af[i], bfr[j], acc[i][j], 0, 0, 0);
    }
    __syncthreads();
  }

  // epilogue: part is block-uniform (n0 multiple of 128, parts 1024-aligned)
  const int part = n0 >> 10;
  const int colbase = n0 & 1023;
  const float* bias_p = part == 0 ? bq : (part == 1 ? bk : bv);
  if (part < 2) {
    u16* dst = part == 0 ? Qb : Kb;
    #pragma unroll
    for (int i = 0; i < 4; ++i)
      #pragma unroll
      for (int j = 0; j < 4; ++j)
        #pragma unroll
        for (int r = 0; r < 4; ++r) {
          int m = m0 + wr * 64 + i * 16 + (lane >> 4) * 4 + r;
          int col = colbase + wc * 64 + j * 16 + lr;
          float val = acc[i][j][r] + bias_p[col];
          int b = m >> 11, s = m & 2047;
          int hh = col >> 6, d = col & 63;
          dst[((size_t)(b * H_ + hh) * S_ + s) * HD_ + d] = f2bf(val);
        }
  } else {
    #pragma unroll
    for (int i = 0; i < 4; ++i)
      #pragma unroll
      for (int j = 0; j < 4; ++j)
        #pragma unroll
        for (int r = 0; r < 4; ++r) {
          int m = m0 + wr * 64 + i * 16 + (lane >> 4) * 4 + r;
          int col = colbase + wc * 64 + j * 16 + lr;
          float val = acc[i][j][r] + bias_p[col];
          int b = m >> 11, s = m & 2047;
          int hh = col >> 6, d = col & 63;
          Vf[((size_t)(b * H_ + hh) * S_ + s) * HD_ + d] = val;
        }
  }
}

// ------- scores: uniform supertiles (64 q-rows x 256 k-cols), atomic Z -------
// Z[bh][q] += sum_{k in chunk, k>=q} exp(s_qk); Ed written by diagonal blocks.
__global__ __launch_bounds__(256) void scores_z_kernel(
    const u16* __restrict__ Qb, const u16* __restrict__ Kb,
    float* __restrict__ Z, float* __restrict__ Ed) {
  int bh = blockIdx.y;
  int t = blockIdx.x;                 // 0..143
  int g = 0;
  while (true) { int cnt = 4 * (8 - g); if (t < cnt) break; t -= cnt; ++g; }
  const int qb = g * 4 + (t & 3);     // 64-row strip
  const int c = g + (t >> 2);         // 256-col chunk
  const bool diag = (c == g);

  const int tid = threadIdx.x;
  const int w = tid >> 6, lane = tid & 63;
  const int lr = lane & 15, hi = lane >> 4, lkb = hi * 8;
  const u16* Qh = Qb + (size_t)bh * S_ * HD_;
  const u16* Kh = Kb + (size_t)bh * S_ * HD_;
  const int q0 = qb * 64;

  bf8 a[4][2];
  #pragma unroll
  for (int g2 = 0; g2 < 4; ++g2) {
    a[g2][0] = *(const bf8*)&Qh[(q0 + g2 * 16 + lr) * 64 + lkb];
    a[g2][1] = *(const bf8*)&Qh[(q0 + g2 * 16 + lr) * 64 + 32 + lkb];
  }
  float zacc[4][4];
  #pragma unroll
  for (int g2 = 0; g2 < 4; ++g2)
    #pragma unroll
    for (int r = 0; r < 4; ++r) zacc[g2][r] = 0.f;

  #pragma unroll
  for (int i = 0; i < 4; ++i) {
    int kt = c * 16 + w + i * 4;      // wave-interleaved: 16 tiles / 4 waves
    bf8 b0 = *(const bf8*)&Kh[(kt * 16 + lr) * 64 + lkb];
    bf8 b1 = *(const bf8*)&Kh[(kt * 16 + lr) * 64 + 32 + lkb];
    int kcol = kt * 16 + lr;
    #pragma unroll
    for (int g2 = 0; g2 < 4; ++g2) {
      f4 cc = {0.f, 0.f, 0.f, 0.f};
      cc = __builtin_amdgcn_mfma_f32_16x16x32_bf16(a[g2][0], b0, cc, 0, 0, 0);
      cc = __builtin_amdgcn_mfma_f32_16x16x32_bf16(a[g2][1], b1, cc, 0, 0, 0);
      #pragma unroll
      for (int r = 0; r < 4; ++r) {
        float e = __expf(cc[r] * 0.03125f);   // / sqrt(1024)
        if (diag) {
          int qrow = q0 + g2 * 16 + hi * 4 + r;
          if (kcol > qrow) {
            zacc[g2][r] += e;
          } else if (kcol == qrow) {
            zacc[g2][r] += e;
            Ed[(size_t)bh * S_ + qrow] = e;
          }
        } else {
          zacc[g2][r] += e;
        }
      }
    }
  }

  __shared__ float Zp[4][64];
  #pragma unroll
  for (int g2 = 0; g2 < 4; ++g2) {
    #pragma unroll
    for (int r = 0; r < 4; ++r) {
      float v = zacc[g2][r];
      v += __shfl_xor(v, 1);
      v += __shfl_xor(v, 2);
      v += __shfl_xor(v, 4);
      v += __shfl_xor(v, 8);
      if (lr == 0) Zp[w][g2 * 16 + hi * 4 + r] = v;
    }
  }
  __syncthreads();
  if (tid < 64) {
    float z = Zp[0][tid] + Zp[1][tid] + Zp[2][tid] + Zp[3][tid];
    atomicAdd(&Z[(size_t)bh * S_ + q0 + tid], z);
  }
}

// ---------------- V prefix-sum chain (16-row chunks) ----------------
#define NC_ 128   // chunks per bh (16 rows each)

__global__ __launch_bounds__(64) void vchunk_kernel(
    const float* __restrict__ Vf, float* __restrict__ csum) {
  int bh = blockIdx.y, c = blockIdx.x;
  int d = threadIdx.x;
  const float* vp = Vf + ((size_t)bh * S_ + c * 16) * HD_ + d;
  float s = 0.f;
  #pragma unroll
  for (int r = 0; r < 16; ++r) s += vp[r * HD_];
  csum[((size_t)bh * NC_ + c) * HD_ + d] = s;
}

// per-bh exclusive scan; all loads issued independently, scan in registers
__global__ __launch_bounds__(256) void vprefix_kernel(float* __restrict__ csum) {
  int bh = blockIdx.x;
  int d = threadIdx.x & 63;
  int qt = threadIdx.x >> 6;
  __shared__ float tot[4][64];
  float v[32];
  #pragma unroll
  for (int c = 0; c < 32; ++c)
    v[c] = csum[((size_t)bh * NC_ + qt * 32 + c) * HD_ + d];
  float run = 0.f;
  #pragma unroll
  for (int c = 0; c < 32; ++c) { float t = v[c]; v[c] = run; run += t; }
  tot[qt][d] = run;
  __syncthreads();
  float off = 0.f;
  #pragma unroll
  for (int p = 0; p < 4; ++p) if (p < qt) off += tot[p][d];
  #pragma unroll
  for (int c = 0; c < 32; ++c)
    csum[((size_t)bh * NC_ + qt * 32 + c) * HD_ + d] = v[c] + off;
}

__global__ __launch_bounds__(64) void attn_out_kernel(
    const float* __restrict__ Vf, const float* __restrict__ csum,
    const float* __restrict__ Z, const float* __restrict__ Ed,
    u16* __restrict__ concat) {
  int bh = blockIdx.y, c = blockIdx.x;
  int d = threadIdx.x;
  int b = bh >> 4, h = bh & 15;
  float run = csum[((size_t)bh * NC_ + c) * HD_ + d];
  #pragma unroll
  for (int r = 0; r < 16; ++r) {
    int s = c * 16 + r;
    size_t vi = ((size_t)bh * S_ + s) * HD_ + d;
    float v = Vf[vi];
    float z = Z[(size_t)bh * S_ + s];
    float e = Ed[(size_t)bh * S_ + s];
    float a = (run + e * v) / z;
    concat[(size_t)(b * S_ + s) * D_ + h * HD_ + d] = f2bf(a);
    run += v;
  }
}

// ---------------- output GEMM: out = x + concat @ wo^T + bo ----------------
__global__ __launch_bounds__(256) void gemm_out_kernel(
    const u16* __restrict__ A,    // concat bf16 [4096][1024]
    const u16* __restrict__ W,    // wo bf16 [1024][1024]
    const float* __restrict__ x, const float* __restrict__ bo,
    float* __restrict__ out) {
  __shared__ u16 As[128 * 64];
  __shared__ u16 Bs[128 * 64];
  const int tid = threadIdx.x;
  const int w = tid >> 6, lane = tid & 63;
  const int wr = w >> 1, wc = w & 1;
  const int m0 = blockIdx.y * 128, n0 = blockIdx.x * 128;
  const int lr = lane & 15, lkb = (lane >> 4) * 8;
  f4 zero = {0.f, 0.f, 0.f, 0.f};
  f4 acc[4][4];
  #pragma unroll
  for (int i = 0; i < 4; ++i)
    #pragma unroll
    for (int j = 0; j < 4; ++j) acc[i][j] = zero;

  for (int kt = 0; kt < 16; ++kt) {
    #pragma unroll
    for (int c = 0; c < 4; ++c) {
      int e = c * 2048 + tid * 8;
      int row = e >> 6, col = e & 63;
      load_lds16(A + (size_t)(m0 + row) * 1024 + kt * 64 + col,
                 &As[c * 2048 + w * 512]);
      load_lds16(W + (size_t)(n0 + row) * 1024 + kt * 64 + col,
                 &Bs[c * 2048 + w * 512]);
    }
    __syncthreads();
    #pragma unroll
    for (int kk = 0; kk < 64; kk += 32) {
      bf8 af[4], bfr[4];
      #pragma unroll
      for (int i = 0; i < 4; ++i)
        af[i] = *(const bf8*)&As[(wr * 64 + i * 16 + lr) * 64 + kk + lkb];
      #pragma unroll
      for (int j = 0; j < 4; ++j)
        bfr[j] = *(const bf8*)&Bs[(wc * 64 + j * 16 + lr) * 64 + kk + lkb];
      #pragma unroll
      for (int i = 0; i < 4; ++i)
        #pragma unroll
        for (int j = 0; j < 4; ++j)
          acc[i][j] = __builtin_amdgcn_mfma_f32_16x16x32_bf16(
              af[i], bfr[j], acc[i][j], 0, 0, 0);
    }
    __syncthreads();
  }

  #pragma unroll
  for (int i = 0; i < 4; ++i) {
    #pragma unroll
    for (int j = 0; j < 4; ++j) {
      #pragma unroll
      for (int r = 0; r < 4; ++r) {
        int m = m0 + wr * 64 + i * 16 + (lane >> 4) * 4 + r;
        int n = n0 + wc * 64 + j * 16 + lr;
        size_t oi = (size_t)m * D_ + n;
        out[oi] = x[oi] + acc[i][j][r] + bo[n];
      }
    }
  }
}

extern "C" void kernel_launch(void* const* d_in, const int* in_sizes, int n_in,
                              void* d_out, int out_size, void* d_ws, size_t ws_size,
                              hipStream_t stream) {
  (void)in_sizes; (void)n_in; (void)out_size; (void)ws_size;
  const float* x     = (const float*)d_in[0];
  const float* wq    = (const float*)d_in[1];
  const float* bq    = (const float*)d_in[2];
  const float* wk    = (const float*)d_in[3];
  const float* bk    = (const float*)d_in[4];
  const float* wv    = (const float*)d_in[5];
  const float* bv    = (const float*)d_in[6];
  const float* wo    = (const float*)d_in[7];
  const float* bo    = (const float*)d_in[8];
  const float* gamma = (const float*)d_in[9];
  const float* beta  = (const float*)d_in[10];
  float* out = (float*)d_out;

  char* ws = (char*)d_ws;
  u16* hbf    = (u16*)(ws);
  u16* wqkv   = (u16*)(ws + (8u << 20));
  u16* wobf   = (u16*)(ws + (14u << 20));
  u16* Qb     = (u16*)(ws + (16u << 20));
  u16* Kb     = (u16*)(ws + (24u << 20));
  float* Vf   = (float*)(ws + (32u << 20));
  float* Z    = (float*)(ws + (48u << 20));
  float* Ed   = (float*)(ws + (48u << 20) + (256u << 10));
  float* csum = (float*)(ws);                 // aliases hbf (dead after QKV GEMM)
  u16* concat = (u16*)(ws + (16u << 20));     // aliases Qb (dead after scores)

  ln_kernel<<<dim3(4096), dim3(256), 0, stream>>>(x, gamma, beta, hbf);
  convw_kernel<<<dim3(16384), dim3(256), 0, stream>>>(wq, wk, wv, wo, wqkv, wobf, Z);
  gemm_qkv_kernel<<<dim3(24, 32), dim3(256), 0, stream>>>(hbf, wqkv, bq, bk, bv,
                                                          Qb, Kb, Vf);
  scores_z_kernel<<<dim3(144, 32), dim3(256), 0, stream>>>(Qb, Kb, Z, Ed);
  vchunk_kernel<<<dim3(NC_, 32), dim3(64), 0, stream>>>(Vf, csum);
  vprefix_kernel<<<dim3(32), dim3(256), 0, stream>>>(csum);
  attn_out_kernel<<<dim3(NC_, 32), dim3(64), 0, stream>>>(Vf, csum, Z, Ed, concat);
  gemm_out_kernel<<<dim3(8, 32), dim3(256), 0, stream>>>(concat, wobf, x, bo, out);
}

// Round 5
// 211.926 us; speedup vs baseline: 1.4897x; 1.1174x over previous
//
#include <hip/hip_runtime.h>
#include <stdint.h>

typedef unsigned short u16;
typedef __bf16 bf8 __attribute__((ext_vector_type(8)));
typedef float f4 __attribute__((ext_vector_type(4)));

#define S_ 2048
#define D_ 1024
#define H_ 16
#define HD_ 64
#define M_ 4096

__device__ __forceinline__ u16 f2bf(float f) {
  union { float f; uint32_t u; } v; v.f = f;
  uint32_t u = v.u;
  u += 0x7FFF + ((u >> 16) & 1);   // round-to-nearest-even
  return (u16)(u >> 16);
}

__device__ __forceinline__ void load_lds16(const void* g, void* l) {
  __builtin_amdgcn_global_load_lds(
      (const __attribute__((address_space(1))) void*)g,
      (__attribute__((address_space(3))) void*)l, 16, 0, 0);
}

// stage one 128x32 A-tile + 128x32 B-tile (bf16) into buf (16KB), swizzled
// source so linear gload_lds dest + XOR'd read side are consistent (rule 21).
// phys 16B-slot c holds logical slot c ^ ((row>>1)&3).
__device__ __forceinline__ void stage_ab(
    const u16* __restrict__ A, const u16* __restrict__ B,
    int m0, int n0, int kt, u16* buf, int tid) {
  #pragma unroll
  for (int l = 0; l < 4; ++l) {
    int p = l * 256 + tid;          // 0..1023: 16B units; <512 A, >=512 B
    int q = p & 511;
    int row = q >> 2, c = q & 3;
    int clog = c ^ ((row >> 1) & 3);
    const u16* src = (p >> 9)
        ? (B + (size_t)(n0 + row) * 1024 + kt * 32 + clog * 8)
        : (A + (size_t)(m0 + row) * 1024 + kt * 32 + clog * 8);
    load_lds16(src, buf + p * 8);
  }
}

// ---------------- LayerNorm: x f32 -> h bf16 ----------------
__global__ __launch_bounds__(256) void ln_kernel(
    const float* __restrict__ x, const float* __restrict__ gamma,
    const float* __restrict__ beta, u16* __restrict__ hbf) {
  int row = blockIdx.x;
  int tid = threadIdx.x;
  int w = tid >> 6, lane = tid & 63;
  const float* xr = x + (size_t)row * D_;
  float lv[4];
  float s = 0.f;
  #pragma unroll
  for (int i = 0; i < 4; ++i) { lv[i] = xr[tid + i * 256]; s += lv[i]; }
  __shared__ float red[8];
  #pragma unroll
  for (int off = 32; off >= 1; off >>= 1) s += __shfl_xor(s, off);
  if (lane == 0) red[w] = s;
  __syncthreads();
  float mean = (red[0] + red[1] + red[2] + red[3]) * (1.f / D_);
  float vs = 0.f;
  #pragma unroll
  for (int i = 0; i < 4; ++i) { float d = lv[i] - mean; vs += d * d; }
  #pragma unroll
  for (int off = 32; off >= 1; off >>= 1) vs += __shfl_xor(vs, off);
  if (lane == 0) red[4 + w] = vs;
  __syncthreads();
  float var = (red[4] + red[5] + red[6] + red[7]) * (1.f / D_);
  float rstd = rsqrtf(var + 1e-5f);
  #pragma unroll
  for (int i = 0; i < 4; ++i) {
    int col = tid + i * 256;
    float y = (lv[i] - mean) * rstd * gamma[col] + beta[col];
    hbf[(size_t)row * D_ + col] = f2bf(y);
  }
}

// ------ weight convert f32 -> bf16, x4 vectorized (+ Z init: Z[bh][q]=q) ----
__global__ __launch_bounds__(256) void convw_kernel(
    const float* __restrict__ wq, const float* __restrict__ wk,
    const float* __restrict__ wv, const float* __restrict__ wo,
    u16* __restrict__ wqkv, u16* __restrict__ wobf, float* __restrict__ Z) {
  int i4 = blockIdx.x * 256 + threadIdx.x;   // 0 .. 1M-1
  int base = i4 * 4;
  int part = base >> 20;
  int off = base & 0xFFFFF;
  const float* src = part == 0 ? wq : part == 1 ? wk : part == 2 ? wv : wo;
  float4 v = *(const float4*)(src + off);
  ushort4 o;
  o.x = f2bf(v.x); o.y = f2bf(v.y); o.z = f2bf(v.z); o.w = f2bf(v.w);
  if (part < 3) *(ushort4*)(wqkv + base) = o;
  else *(ushort4*)(wobf + off) = o;
  if (i4 < 32 * S_) Z[i4] = (float)(i4 & (S_ - 1));
}

// ---- QKV GEMM: C[4096,3072] = h @ Wqkv^T; 4-deep ring pipeline, BK=32 ----
__global__ __launch_bounds__(256, 2) void gemm_qkv_kernel(
    const u16* __restrict__ A,    // [4096][1024] bf16
    const u16* __restrict__ W,    // [3072][1024] bf16
    const float* __restrict__ bq, const float* __restrict__ bk,
    const float* __restrict__ bv,
    u16* __restrict__ Qb, u16* __restrict__ Kb, float* __restrict__ Vf) {
  __shared__ u16 smem[4 * 8192];   // 4 bufs x (A 8KB + B 8KB)
  const int tid = threadIdx.x;
  const int w = tid >> 6, lane = tid & 63;
  const int wr = w >> 1, wc = w & 1;
  const int lr = lane & 15, hi = lane >> 4;
  const int kswz = (hi ^ ((lr >> 1) & 3)) * 8;   // swizzled 16B slot (in u16)

  // XCD swizzle: 768 blocks, 96/XCD, m-fastest chunks (B-panel reuse in L2)
  int bid = blockIdx.x;
  int swz = (bid & 7) * 96 + (bid >> 3);
  const int m0 = (swz & 31) * 128;
  const int n0 = (swz >> 5) * 128;

  f4 acc[4][4];
  f4 zero = {0.f, 0.f, 0.f, 0.f};
  #pragma unroll
  for (int i = 0; i < 4; ++i)
    #pragma unroll
    for (int j = 0; j < 4; ++j) acc[i][j] = zero;

  stage_ab(A, W, m0, n0, 0, smem, tid);
  stage_ab(A, W, m0, n0, 1, smem + 8192, tid);
  stage_ab(A, W, m0, n0, 2, smem + 16384, tid);

  for (int t = 0; t < 32; ++t) {
    if (t < 30)      asm volatile("s_waitcnt vmcnt(8)\n\ts_barrier" ::: "memory");
    else if (t == 30) asm volatile("s_waitcnt vmcnt(4)\n\ts_barrier" ::: "memory");
    else             asm volatile("s_waitcnt vmcnt(0)\n\ts_barrier" ::: "memory");
    const u16* As = smem + (t & 3) * 8192;
    const u16* Bs = As + 4096;
    bf8 av[4], bvv[4];
    #pragma unroll
    for (int i = 0; i < 4; ++i)
      av[i] = *(const bf8*)&As[(wr * 64 + i * 16 + lr) * 32 + kswz];
    #pragma unroll
    for (int j = 0; j < 4; ++j)
      bvv[j] = *(const bf8*)&Bs[(wc * 64 + j * 16 + lr) * 32 + kswz];
    if (t < 29) stage_ab(A, W, m0, n0, t + 3, smem + ((t + 3) & 3) * 8192, tid);
    __builtin_amdgcn_s_setprio(1);
    #pragma unroll
    for (int i = 0; i < 4; ++i)
      #pragma unroll
      for (int j = 0; j < 4; ++j)
        acc[i][j] = __builtin_amdgcn_mfma_f32_16x16x32_bf16(
            av[i], bvv[j], acc[i][j], 0, 0, 0);
    __builtin_amdgcn_s_setprio(0);
  }

  // epilogue: part is block-uniform (parts 1024-aligned, n0 multiple of 128)
  const int part = n0 >> 10;
  const int colbase = n0 & 1023;
  const float* bias_p = part == 0 ? bq : (part == 1 ? bk : bv);
  if (part < 2) {
    u16* dst = part == 0 ? Qb : Kb;
    #pragma unroll
    for (int i = 0; i < 4; ++i)
      #pragma unroll
      for (int j = 0; j < 4; ++j)
        #pragma unroll
        for (int r = 0; r < 4; ++r) {
          int m = m0 + wr * 64 + i * 16 + hi * 4 + r;
          int col = colbase + wc * 64 + j * 16 + lr;
          float val = acc[i][j][r] + bias_p[col];
          int b = m >> 11, s = m & 2047;
          int hh = col >> 6, d = col & 63;
          dst[((size_t)(b * H_ + hh) * S_ + s) * HD_ + d] = f2bf(val);
        }
  } else {
    #pragma unroll
    for (int i = 0; i < 4; ++i)
      #pragma unroll
      for (int j = 0; j < 4; ++j)
        #pragma unroll
        for (int r = 0; r < 4; ++r) {
          int m = m0 + wr * 64 + i * 16 + hi * 4 + r;
          int col = colbase + wc * 64 + j * 16 + lr;
          float val = acc[i][j][r] + bias_p[col];
          int b = m >> 11, s = m & 2047;
          int hh = col >> 6, d = col & 63;
          Vf[((size_t)(b * H_ + hh) * S_ + s) * HD_ + d] = val;
        }
  }
}

// ------- scores: uniform supertiles (64 q-rows x 256 k-cols), atomic Z -------
__global__ __launch_bounds__(256) void scores_z_kernel(
    const u16* __restrict__ Qb, const u16* __restrict__ Kb,
    float* __restrict__ Z, float* __restrict__ Ed) {
  int bh = blockIdx.y;
  int t = blockIdx.x;                 // 0..143
  int g = 0;
  while (true) { int cnt = 4 * (8 - g); if (t < cnt) break; t -= cnt; ++g; }
  const int qb = g * 4 + (t & 3);     // 64-row strip
  const int c = g + (t >> 2);         // 256-col chunk
  const bool diag = (c == g);

  const int tid = threadIdx.x;
  const int w = tid >> 6, lane = tid & 63;
  const int lr = lane & 15, hi = lane >> 4, lkb = hi * 8;
  const u16* Qh = Qb + (size_t)bh * S_ * HD_;
  const u16* Kh = Kb + (size_t)bh * S_ * HD_;
  const int q0 = qb * 64;

  bf8 a[4][2];
  #pragma unroll
  for (int g2 = 0; g2 < 4; ++g2) {
    a[g2][0] = *(const bf8*)&Qh[(q0 + g2 * 16 + lr) * 64 + lkb];
    a[g2][1] = *(const bf8*)&Qh[(q0 + g2 * 16 + lr) * 64 + 32 + lkb];
  }
  float zacc[4][4];
  #pragma unroll
  for (int g2 = 0; g2 < 4; ++g2)
    #pragma unroll
    for (int r = 0; r < 4; ++r) zacc[g2][r] = 0.f;

  #pragma unroll
  for (int i = 0; i < 4; ++i) {
    int kt = c * 16 + w + i * 4;      // wave-interleaved: 16 tiles / 4 waves
    bf8 b0 = *(const bf8*)&Kh[(kt * 16 + lr) * 64 + lkb];
    bf8 b1 = *(const bf8*)&Kh[(kt * 16 + lr) * 64 + 32 + lkb];
    int kcol = kt * 16 + lr;
    #pragma unroll
    for (int g2 = 0; g2 < 4; ++g2) {
      f4 cc = {0.f, 0.f, 0.f, 0.f};
      cc = __builtin_amdgcn_mfma_f32_16x16x32_bf16(a[g2][0], b0, cc, 0, 0, 0);
      cc = __builtin_amdgcn_mfma_f32_16x16x32_bf16(a[g2][1], b1, cc, 0, 0, 0);
      #pragma unroll
      for (int r = 0; r < 4; ++r) {
        float e = __expf(cc[r] * 0.03125f);   // / sqrt(1024)
        if (diag) {
          int qrow = q0 + g2 * 16 + hi * 4 + r;
          if (kcol > qrow) {
            zacc[g2][r] += e;
          } else if (kcol == qrow) {
            zacc[g2][r] += e;
            Ed[(size_t)bh * S_ + qrow] = e;
          }
        } else {
          zacc[g2][r] += e;
        }
      }
    }
  }

  __shared__ float Zp[4][64];
  #pragma unroll
  for (int g2 = 0; g2 < 4; ++g2) {
    #pragma unroll
    for (int r = 0; r < 4; ++r) {
      float v = zacc[g2][r];
      v += __shfl_xor(v, 1);
      v += __shfl_xor(v, 2);
      v += __shfl_xor(v, 4);
      v += __shfl_xor(v, 8);
      if (lr == 0) Zp[w][g2 * 16 + hi * 4 + r] = v;
    }
  }
  __syncthreads();
  if (tid < 64) {
    float z = Zp[0][tid] + Zp[1][tid] + Zp[2][tid] + Zp[3][tid];
    atomicAdd(&Z[(size_t)bh * S_ + q0 + tid], z);
  }
}

// ---------------- V prefix-sum chain (16-row chunks) ----------------
#define NC_ 128   // chunks per bh (16 rows each)

__global__ __launch_bounds__(64) void vchunk_kernel(
    const float* __restrict__ Vf, float* __restrict__ csum) {
  int bh = blockIdx.y, c = blockIdx.x;
  int d = threadIdx.x;
  const float* vp = Vf + ((size_t)bh * S_ + c * 16) * HD_ + d;
  float s = 0.f;
  #pragma unroll
  for (int r = 0; r < 16; ++r) s += vp[r * HD_];
  csum[((size_t)bh * NC_ + c) * HD_ + d] = s;
}

// per-bh exclusive scan; all loads issued independently, scan in registers
__global__ __launch_bounds__(256) void vprefix_kernel(float* __restrict__ csum) {
  int bh = blockIdx.x;
  int d = threadIdx.x & 63;
  int qt = threadIdx.x >> 6;
  __shared__ float tot[4][64];
  float v[32];
  #pragma unroll
  for (int c = 0; c < 32; ++c)
    v[c] = csum[((size_t)bh * NC_ + qt * 32 + c) * HD_ + d];
  float run = 0.f;
  #pragma unroll
  for (int c = 0; c < 32; ++c) { float t = v[c]; v[c] = run; run += t; }
  tot[qt][d] = run;
  __syncthreads();
  float off = 0.f;
  #pragma unroll
  for (int p = 0; p < 4; ++p) if (p < qt) off += tot[p][d];
  #pragma unroll
  for (int c = 0; c < 32; ++c)
    csum[((size_t)bh * NC_ + qt * 32 + c) * HD_ + d] = v[c] + off;
}

__global__ __launch_bounds__(64) void attn_out_kernel(
    const float* __restrict__ Vf, const float* __restrict__ csum,
    const float* __restrict__ Z, const float* __restrict__ Ed,
    u16* __restrict__ concat) {
  int bh = blockIdx.y, c = blockIdx.x;
  int d = threadIdx.x;
  int b = bh >> 4, h = bh & 15;
  float run = csum[((size_t)bh * NC_ + c) * HD_ + d];
  #pragma unroll
  for (int r = 0; r < 16; ++r) {
    int s = c * 16 + r;
    size_t vi = ((size_t)bh * S_ + s) * HD_ + d;
    float v = Vf[vi];
    float z = Z[(size_t)bh * S_ + s];
    float e = Ed[(size_t)bh * S_ + s];
    float a = (run + e * v) / z;
    concat[(size_t)(b * S_ + s) * D_ + h * HD_ + d] = f2bf(a);
    run += v;
  }
}

// -- output GEMM: out = x + concat @ wo^T + bo; 4-deep ring pipeline, BK=32 --
__global__ __launch_bounds__(256, 2) void gemm_out_kernel(
    const u16* __restrict__ A,    // concat bf16 [4096][1024]
    const u16* __restrict__ W,    // wo bf16 [1024][1024]
    const float* __restrict__ x, const float* __restrict__ bo,
    float* __restrict__ out) {
  __shared__ u16 smem[4 * 8192];
  const int tid = threadIdx.x;
  const int w = tid >> 6, lane = tid & 63;
  const int wr = w >> 1, wc = w & 1;
  const int lr = lane & 15, hi = lane >> 4;
  const int kswz = (hi ^ ((lr >> 1) & 3)) * 8;

  // XCD swizzle: 256 blocks, 32/XCD
  int bid = blockIdx.x;
  int swz = (bid & 7) * 32 + (bid >> 3);
  const int m0 = (swz & 31) * 128;
  const int n0 = (swz >> 5) * 128;

  f4 acc[4][4];
  f4 zero = {0.f, 0.f, 0.f, 0.f};
  #pragma unroll
  for (int i = 0; i < 4; ++i)
    #pragma unroll
    for (int j = 0; j < 4; ++j) acc[i][j] = zero;

  stage_ab(A, W, m0, n0, 0, smem, tid);
  stage_ab(A, W, m0, n0, 1, smem + 8192, tid);
  stage_ab(A, W, m0, n0, 2, smem + 16384, tid);

  for (int t = 0; t < 32; ++t) {
    if (t < 30)      asm volatile("s_waitcnt vmcnt(8)\n\ts_barrier" ::: "memory");
    else if (t == 30) asm volatile("s_waitcnt vmcnt(4)\n\ts_barrier" ::: "memory");
    else             asm volatile("s_waitcnt vmcnt(0)\n\ts_barrier" ::: "memory");
    const u16* As = smem + (t & 3) * 8192;
    const u16* Bs = As + 4096;
    bf8 av[4], bvv[4];
    #pragma unroll
    for (int i = 0; i < 4; ++i)
      av[i] = *(const bf8*)&As[(wr * 64 + i * 16 + lr) * 32 + kswz];
    #pragma unroll
    for (int j = 0; j < 4; ++j)
      bvv[j] = *(const bf8*)&Bs[(wc * 64 + j * 16 + lr) * 32 + kswz];
    if (t < 29) stage_ab(A, W, m0, n0, t + 3, smem + ((t + 3) & 3) * 8192, tid);
    __builtin_amdgcn_s_setprio(1);
    #pragma unroll
    for (int i = 0; i < 4; ++i)
      #pragma unroll
      for (int j = 0; j < 4; ++j)
        acc[i][j] = __builtin_amdgcn_mfma_f32_16x16x32_bf16(
            av[i], bvv[j], acc[i][j], 0, 0, 0);
    __builtin_amdgcn_s_setprio(0);
  }

  #pragma unroll
  for (int i = 0; i < 4; ++i)
    #pragma unroll
    for (int j = 0; j < 4; ++j)
      #pragma unroll
      for (int r = 0; r < 4; ++r) {
        int m = m0 + wr * 64 + i * 16 + hi * 4 + r;
        int n = n0 + wc * 64 + j * 16 + lr;
        size_t oi = (size_t)m * D_ + n;
        out[oi] = x[oi] + acc[i][j][r] + bo[n];
      }
}

extern "C" void kernel_launch(void* const* d_in, const int* in_sizes, int n_in,
                              void* d_out, int out_size, void* d_ws, size_t ws_size,
                              hipStream_t stream) {
  (void)in_sizes; (void)n_in; (void)out_size; (void)ws_size;
  const float* x     = (const float*)d_in[0];
  const float* wq    = (const float*)d_in[1];
  const float* bq    = (const float*)d_in[2];
  const float* wk    = (const float*)d_in[3];
  const float* bk    = (const float*)d_in[4];
  const float* wv    = (const float*)d_in[5];
  const float* bv    = (const float*)d_in[6];
  const float* wo    = (const float*)d_in[7];
  const float* bo    = (const float*)d_in[8];
  const float* gamma = (const float*)d_in[9];
  const float* beta  = (const float*)d_in[10];
  float* out = (float*)d_out;

  char* ws = (char*)d_ws;
  u16* hbf    = (u16*)(ws);
  u16* wqkv   = (u16*)(ws + (8u << 20));
  u16* wobf   = (u16*)(ws + (14u << 20));
  u16* Qb     = (u16*)(ws + (16u << 20));
  u16* Kb     = (u16*)(ws + (24u << 20));
  float* Vf   = (float*)(ws + (32u << 20));
  float* Z    = (float*)(ws + (48u << 20));
  float* Ed   = (float*)(ws + (48u << 20) + (256u << 10));
  float* csum = (float*)(ws);                 // aliases hbf (dead after QKV GEMM)
  u16* concat = (u16*)(ws + (16u << 20));     // aliases Qb (dead after scores)

  ln_kernel<<<dim3(4096), dim3(256), 0, stream>>>(x, gamma, beta, hbf);
  convw_kernel<<<dim3(4096), dim3(256), 0, stream>>>(wq, wk, wv, wo, wqkv, wobf, Z);
  gemm_qkv_kernel<<<dim3(768), dim3(256), 0, stream>>>(hbf, wqkv, bq, bk, bv,
                                                       Qb, Kb, Vf);
  scores_z_kernel<<<dim3(144, 32), dim3(256), 0, stream>>>(Qb, Kb, Z, Ed);
  vchunk_kernel<<<dim3(NC_, 32), dim3(64), 0, stream>>>(Vf, csum);
  vprefix_kernel<<<dim3(32), dim3(256), 0, stream>>>(csum);
  attn_out_kernel<<<dim3(NC_, 32), dim3(64), 0, stream>>>(Vf, csum, Z, Ed, concat);
  gemm_out_kernel<<<dim3(256), dim3(256), 0, stream>>>(concat, wobf, x, bo, out);
}